// Round 5
// baseline (374.751 us; speedup 1.0000x reference)
//
#include <hip/hip_runtime.h>
#include <float.h>

#define NB 32
#define D  2048
#define NC 1023
#define RPB 8   // attn rows per block

typedef float f32x4 __attribute__((ext_vector_type(4)));

// ws layout (float offsets)
#define OFF_LN   0                      // ln_feat [NB*D]
#define OFF_SW   (NB*D)                 // float2 sw[NB][NC]
#define OFF_MM   (OFF_SW + 2*NB*NC)     // smax[NB], smin[NB]
#define OFF_OUT1 (OFF_MM + 64)          // out1 [NB*D]  (131072)
#define OFF_LN2  (OFF_OUT1 + NB*D)      // ln2  [NB*D]
#define OFF_H    (OFF_LN2 + NB*D)       // h    [NB*D]

__device__ __forceinline__ float wred_sum(float x){
  #pragma unroll
  for (int o = 32; o; o >>= 1) x += __shfl_xor(x, o);
  return x;
}

// ---------------------------------------------------------------------------
// Kernel 1: per-batch prep. LN1, gather, kq/vw fold, s/w vectors, smax/smin.
// ---------------------------------------------------------------------------
__global__ __launch_bounds__(256) void prep_kernel(
    const float* __restrict__ feat, const int* __restrict__ idx,
    const float* __restrict__ ln_w, const float* __restrict__ ln_b,
    const float* __restrict__ q_w,  const float* __restrict__ k_w,
    const float* __restrict__ v_w,  const float* __restrict__ conv_w,
    float* __restrict__ ws)
{
  __shared__ float sh_feat[D];
  __shared__ float sh_shuf[D];
  __shared__ float red_s[4][2];
  __shared__ float red_k[4][8];
  __shared__ float red_mm[4][2];

  const int b = blockIdx.x;
  const int t = threadIdx.x;
  const int wid = t >> 6;

  const float4* fb4 = (const float4*)(feat + b * D);
  float4* sf4 = (float4*)sh_feat;
  float4 fv[2];
  float s1 = 0.f, s2 = 0.f;
  #pragma unroll
  for (int j = 0; j < 2; ++j) {
    float4 v = fb4[t + j * 256];
    fv[j] = v;
    sf4[t + j * 256] = v;
    s1 += (v.x + v.y) + (v.z + v.w);
    s2 += fmaf(v.x, v.x, fmaf(v.y, v.y, fmaf(v.z, v.z, v.w * v.w)));
  }

  float pk[4] = {0,0,0,0}, pv[4] = {0,0,0,0};
  if (t < 128) {
    float qv = q_w[t], cv = conv_w[t];
    #pragma unroll
    for (int j = 0; j < 4; ++j) {
      pk[j] = qv * k_w[t * 4 + j];
      pv[j] = cv * v_w[t * 4 + j];
    }
  }
  s1 = wred_sum(s1); s2 = wred_sum(s2);
  #pragma unroll
  for (int j = 0; j < 4; ++j) { pk[j] = wred_sum(pk[j]); pv[j] = wred_sum(pv[j]); }
  if ((t & 63) == 0) {
    red_s[wid][0] = s1; red_s[wid][1] = s2;
    #pragma unroll
    for (int j = 0; j < 4; ++j) { red_k[wid][j] = pk[j]; red_k[wid][4 + j] = pv[j]; }
  }
  __syncthreads();

  const float S1 = red_s[0][0] + red_s[1][0] + red_s[2][0] + red_s[3][0];
  const float S2 = red_s[0][1] + red_s[1][1] + red_s[2][1] + red_s[3][1];
  float kq[4], vw[4];
  #pragma unroll
  for (int j = 0; j < 4; ++j) {
    kq[j] = red_k[0][j] + red_k[1][j] + red_k[2][j] + red_k[3][j];
    vw[j] = red_k[0][4+j] + red_k[1][4+j] + red_k[2][4+j] + red_k[3][4+j];
  }
  const float mean = S1 * (1.f / D);
  const float rstd = rsqrtf(S2 * (1.f / D) - mean * mean + 1e-5f);

  float* lnp = ws + OFF_LN + b * D;
  const float4* lw4 = (const float4*)ln_w;
  const float4* lb4 = (const float4*)ln_b;
  #pragma unroll
  for (int j = 0; j < 2; ++j) {
    int i = t + j * 256;
    float4 v = fv[j], w = lw4[i], bb = lb4[i], o;
    o.x = (v.x - mean) * rstd * w.x + bb.x;
    o.y = (v.y - mean) * rstd * w.y + bb.y;
    o.z = (v.z - mean) * rstd * w.z + bb.z;
    o.w = (v.w - mean) * rstd * w.w + bb.w;
    ((float4*)lnp)[i] = o;
  }

  #pragma unroll
  for (int j = 0; j < 8; ++j) {
    int i = t + j * 256;
    sh_shuf[i] = sh_feat[idx[i]];
  }
  __syncthreads();

  float2* swp = (float2*)(ws + OFF_SW) + b * NC;
  float lmax = -FLT_MAX, lmin = FLT_MAX;
  #pragma unroll
  for (int j = 0; j < 4; ++j) {
    int c = t + j * 256;
    if (c < NC) {
      float a0 = sh_shuf[2*c], a1 = sh_shuf[2*c+1], a2 = sh_shuf[2*c+2], a3 = sh_shuf[2*c+3];
      float sv = fmaf(a0, kq[0], fmaf(a1, kq[1], fmaf(a2, kq[2], a3 * kq[3])));
      float wv = fmaf(a0, vw[0], fmaf(a1, vw[1], fmaf(a2, vw[2], a3 * vw[3])));
      float2 p; p.x = sv; p.y = wv;
      swp[c] = p;
      lmax = fmaxf(lmax, sv);
      lmin = fminf(lmin, sv);
    }
  }
  #pragma unroll
  for (int o = 32; o; o >>= 1) {
    lmax = fmaxf(lmax, __shfl_xor(lmax, o));
    lmin = fminf(lmin, __shfl_xor(lmin, o));
  }
  if ((t & 63) == 0) { red_mm[wid][0] = lmax; red_mm[wid][1] = lmin; }
  __syncthreads();
  if (t == 0) {
    ws[OFF_MM + b]      = fmaxf(fmaxf(red_mm[0][0], red_mm[1][0]), fmaxf(red_mm[2][0], red_mm[3][0]));
    ws[OFF_MM + NB + b] = fminf(fminf(red_mm[0][1], red_mm[1][1]), fminf(red_mm[2][1], red_mm[3][1]));
  }
}

// ---------------------------------------------------------------------------
// Kernel 2: 8 rows per block. sw staged in LDS once; exp pass into flat LDS;
// contiguous aligned float4 nontemporal stores.
// ---------------------------------------------------------------------------
__global__ __launch_bounds__(256) void attn_kernel(
    const float* __restrict__ feat, float* __restrict__ ws,
    float* __restrict__ out)
{
  __shared__ float ebuf[RPB * 1024];
  __shared__ float2 sws[1024];
  __shared__ float sinv[RPB];

  const int row0 = blockIdx.x * RPB;
  const int b = row0 >> 11;
  const int t = threadIdx.x;
  const int wid = t >> 6, lane = t & 63;

  const float smax = ws[OFF_MM + b], smin = ws[OFF_MM + NB + b];
  const float2* swg = (const float2*)(ws + OFF_SW) + b * NC;
  #pragma unroll
  for (int j = 0; j < 4; ++j) {
    int c = t + j * 256;
    if (c < NC) sws[c] = swg[c];
  }
  __syncthreads();

  #pragma unroll
  for (int rr = 0; rr < 2; ++rr) {
    const int r = wid * 2 + rr;
    const int row = row0 + r;
    const float alpha = ws[OFF_LN + row];
    const float m = (alpha >= 0.f) ? alpha * smax : alpha * smin;
    float* eb = ebuf + r * NC;
    float l = 0.f, acc = 0.f;
    #pragma unroll
    for (int j = 0; j < 16; ++j) {
      int c = lane + j * 64;
      if (c < NC) {
        float2 p = sws[c];
        float e = __expf(fmaf(alpha, p.x, -m));
        eb[c] = e;
        l += e;
        acc = fmaf(e, p.y, acc);
      }
    }
    #pragma unroll
    for (int o = 32; o; o >>= 1) { l += __shfl_xor(l, o); acc += __shfl_xor(acc, o); }
    if (lane == 0) {
      float inv = 1.f / l;
      sinv[r] = inv;
      ws[OFF_OUT1 + row] = fmaf(acc, inv, feat[row]);
    }
  }
  __syncthreads();

  f32x4* base = (f32x4*)(out + NB * D + (size_t)row0 * NC);
  const f32x4* eb4 = (const f32x4*)ebuf;
  #pragma unroll
  for (int j = 0; j < 8; ++j) {
    int i4 = t + j * 256;
    if (i4 < 2046) {
      f32x4 v = eb4[i4];
      int g = i4 * 4;
      int r0 = g / NC, r1 = (g + 1) / NC, r2 = (g + 2) / NC, r3 = (g + 3) / NC;
      v.x *= sinv[r0]; v.y *= sinv[r1]; v.z *= sinv[r2]; v.w *= sinv[r3];
      __builtin_nontemporal_store(v, base + i4);
    }
  }
}

// ---------------------------------------------------------------------------
// Kernel 3: LN2 over out1; init h = w1_b, init out = out1 + w2_b.
// ---------------------------------------------------------------------------
__global__ __launch_bounds__(256) void ln2_init_kernel(
    const float* __restrict__ bnw, const float* __restrict__ bnb,
    const float* __restrict__ w1b, const float* __restrict__ w2b,
    float* __restrict__ ws, float* __restrict__ out)
{
  __shared__ float red_s[4][2];
  const int b = blockIdx.x, t = threadIdx.x;
  const int wid = t >> 6;
  const float4* x4 = (const float4*)(ws + OFF_OUT1 + b * D);
  float4 xv[2];
  float s1 = 0.f, s2 = 0.f;
  #pragma unroll
  for (int j = 0; j < 2; ++j) {
    float4 v = x4[t + j * 256];
    xv[j] = v;
    s1 += (v.x + v.y) + (v.z + v.w);
    s2 += fmaf(v.x, v.x, fmaf(v.y, v.y, fmaf(v.z, v.z, v.w * v.w)));
  }
  s1 = wred_sum(s1); s2 = wred_sum(s2);
  if ((t & 63) == 0) { red_s[wid][0] = s1; red_s[wid][1] = s2; }
  __syncthreads();
  const float S1 = red_s[0][0] + red_s[1][0] + red_s[2][0] + red_s[3][0];
  const float S2 = red_s[0][1] + red_s[1][1] + red_s[2][1] + red_s[3][1];
  const float mean = S1 * (1.f / D);
  const float rstd = rsqrtf(S2 * (1.f / D) - mean * mean + 1e-6f);

  float4* ln2p = (float4*)(ws + OFF_LN2 + b * D);
  float4* hp   = (float4*)(ws + OFF_H   + b * D);
  float4* op   = (float4*)out + b * (D / 4);
  const float4* bw4 = (const float4*)bnw;
  const float4* bb4 = (const float4*)bnb;
  const float4* w1b4 = (const float4*)w1b;
  const float4* w2b4 = (const float4*)w2b;
  #pragma unroll
  for (int j = 0; j < 2; ++j) {
    int i = t + j * 256;
    float4 v = xv[j], w = bw4[i], bb = bb4[i], o;
    o.x = (v.x - mean) * rstd * w.x + bb.x;
    o.y = (v.y - mean) * rstd * w.y + bb.y;
    o.z = (v.z - mean) * rstd * w.z + bb.z;
    o.w = (v.w - mean) * rstd * w.w + bb.w;
    ln2p[i] = o;
    hp[i] = w1b4[i];
    float4 w2 = w2b4[i], oo;
    oo.x = v.x + w2.x; oo.y = v.y + w2.y; oo.z = v.z + w2.z; oo.w = v.w + w2.w;
    op[i] = oo;
  }
}

// ---------------------------------------------------------------------------
// Kernels 4/5: out[m,n] += sum_k X[m,k]*W[n,k]   (M=32, N=K=2048)
// grid = 32 nb (N=64) x 16 kb (K=128), 128 threads, 4x4 register tiles.
// X row-major LDS (broadcast reads). W transposed+XOR-swizzled LDS so the
// n-contiguous ds_read_b128 is conflict-free. RELU applied to X on load.
// ---------------------------------------------------------------------------
template<int RELU>
__global__ __launch_bounds__(128) void gemm_kernel(
    const float* __restrict__ X, const float* __restrict__ W,
    float* __restrict__ out)
{
  __shared__ float xs[32][132];     // 32 m x 128 k (pad 132)  16.9 KB
  __shared__ float wtT[128 * 64];   // [k][n] swizzled         32 KB
  const int nb = blockIdx.x & 31;
  const int kb = blockIdx.x >> 5;   // 0..15
  const int n0 = nb * 64;
  const int k0 = kb * 128;
  const int t = threadIdx.x;        // 0..127
  const int tm = t >> 4;            // 0..7  -> m = tm*4..+4
  const int tn = t & 15;            // 0..15 -> n = n0 + tn*4..+4

  // stage X: 32 x 128 = 1024 float4, 8 per thread
  #pragma unroll
  for (int jj = 0; jj < 8; ++jj) {
    int idx = jj * 128 + t;
    int m_r = idx >> 5, q_r = idx & 31;
    float4 v = *(const float4*)(X + m_r * 2048 + k0 + q_r * 4);
    if (RELU) {
      v.x = fmaxf(v.x, 0.f); v.y = fmaxf(v.y, 0.f);
      v.z = fmaxf(v.z, 0.f); v.w = fmaxf(v.w, 0.f);
    }
    *(float4*)(&xs[m_r][q_r * 4]) = v;
  }
  // stage W transposed + quad-XOR swizzle: 64 n x 128 k = 2048 float4, 16/thread
  #pragma unroll
  for (int jj = 0; jj < 16; ++jj) {
    int idx = jj * 128 + t;
    int n_r = idx >> 5, q_r = idx & 31;
    float4 v = *(const float4*)(W + (n0 + n_r) * 2048 + k0 + q_r * 4);
    float vv[4] = {v.x, v.y, v.z, v.w};
    #pragma unroll
    for (int c = 0; c < 4; ++c) {
      int kk = q_r * 4 + c;
      wtT[kk * 64 + ((((n_r >> 2) ^ (kk & 15)) << 2) | (n_r & 3))] = vv[c];
    }
  }
  __syncthreads();

  float4 acc0 = {0,0,0,0}, acc1 = {0,0,0,0}, acc2 = {0,0,0,0}, acc3 = {0,0,0,0};
  #pragma unroll 2
  for (int kq = 0; kq < 32; ++kq) {
    float4 xq0 = *(const float4*)(&xs[tm * 4 + 0][kq * 4]);
    float4 xq1 = *(const float4*)(&xs[tm * 4 + 1][kq * 4]);
    float4 xq2 = *(const float4*)(&xs[tm * 4 + 2][kq * 4]);
    float4 xq3 = *(const float4*)(&xs[tm * 4 + 3][kq * 4]);
    #pragma unroll
    for (int c = 0; c < 4; ++c) {
      int kk = kq * 4 + c;
      float4 wv = *(const float4*)(&wtT[kk * 64 + ((tn ^ (kk & 15)) << 2)]);
      float x0 = (c==0)?xq0.x:(c==1)?xq0.y:(c==2)?xq0.z:xq0.w;
      float x1 = (c==0)?xq1.x:(c==1)?xq1.y:(c==2)?xq1.z:xq1.w;
      float x2 = (c==0)?xq2.x:(c==1)?xq2.y:(c==2)?xq2.z:xq2.w;
      float x3 = (c==0)?xq3.x:(c==1)?xq3.y:(c==2)?xq3.z:xq3.w;
      acc0.x = fmaf(x0, wv.x, acc0.x); acc0.y = fmaf(x0, wv.y, acc0.y);
      acc0.z = fmaf(x0, wv.z, acc0.z); acc0.w = fmaf(x0, wv.w, acc0.w);
      acc1.x = fmaf(x1, wv.x, acc1.x); acc1.y = fmaf(x1, wv.y, acc1.y);
      acc1.z = fmaf(x1, wv.z, acc1.z); acc1.w = fmaf(x1, wv.w, acc1.w);
      acc2.x = fmaf(x2, wv.x, acc2.x); acc2.y = fmaf(x2, wv.y, acc2.y);
      acc2.z = fmaf(x2, wv.z, acc2.z); acc2.w = fmaf(x2, wv.w, acc2.w);
      acc3.x = fmaf(x3, wv.x, acc3.x); acc3.y = fmaf(x3, wv.y, acc3.y);
      acc3.z = fmaf(x3, wv.z, acc3.z); acc3.w = fmaf(x3, wv.w, acc3.w);
    }
  }

  float* op0 = out + (tm * 4 + 0) * 2048 + n0 + tn * 4;
  float* op1 = op0 + 2048;
  float* op2 = op1 + 2048;
  float* op3 = op2 + 2048;
  atomicAdd(op0+0, acc0.x); atomicAdd(op0+1, acc0.y); atomicAdd(op0+2, acc0.z); atomicAdd(op0+3, acc0.w);
  atomicAdd(op1+0, acc1.x); atomicAdd(op1+1, acc1.y); atomicAdd(op1+2, acc1.z); atomicAdd(op1+3, acc1.w);
  atomicAdd(op2+0, acc2.x); atomicAdd(op2+1, acc2.y); atomicAdd(op2+2, acc2.z); atomicAdd(op2+3, acc2.w);
  atomicAdd(op3+0, acc3.x); atomicAdd(op3+1, acc3.y); atomicAdd(op3+2, acc3.z); atomicAdd(op3+3, acc3.w);
}

// ---------------------------------------------------------------------------
extern "C" void kernel_launch(void* const* d_in, const int* in_sizes, int n_in,
                              void* d_out, int out_size, void* d_ws, size_t ws_size,
                              hipStream_t stream)
{
  (void)in_sizes; (void)n_in; (void)out_size; (void)ws_size;
  const float* feat   = (const float*)d_in[0];
  const int*   idx    = (const int*)d_in[1];
  const float* ln_w   = (const float*)d_in[2];
  const float* ln_b   = (const float*)d_in[3];
  const float* q_w    = (const float*)d_in[4];
  const float* k_w    = (const float*)d_in[5];
  const float* v_w    = (const float*)d_in[6];
  const float* conv_w = (const float*)d_in[7];
  const float* bnw    = (const float*)d_in[8];
  const float* bnb    = (const float*)d_in[9];
  const float* w1w    = (const float*)d_in[10];
  const float* w1b    = (const float*)d_in[11];
  const float* w2w    = (const float*)d_in[12];
  const float* w2b    = (const float*)d_in[13];
  float* out = (float*)d_out;
  float* ws  = (float*)d_ws;

  prep_kernel<<<dim3(NB), dim3(256), 0, stream>>>(feat, idx, ln_w, ln_b, q_w, k_w, v_w, conv_w, ws);
  attn_kernel<<<dim3(NB * D / RPB), dim3(256), 0, stream>>>(feat, ws, out);
  ln2_init_kernel<<<dim3(NB), dim3(256), 0, stream>>>(bnw, bnb, w1b, w2b, ws, out);
  gemm_kernel<0><<<dim3(512), dim3(128), 0, stream>>>(ws + OFF_LN2, w1w, ws + OFF_H);
  gemm_kernel<1><<<dim3(512), dim3(128), 0, stream>>>(ws + OFF_H, w2w, out);
}

// Round 6
// 359.885 us; speedup vs baseline: 1.0413x; 1.0413x over previous
//
#include <hip/hip_runtime.h>
#include <float.h>

#define NB 32
#define D  2048
#define NC 1023
#define RPB 8   // attn rows per block

typedef float f32x4 __attribute__((ext_vector_type(4)));

// ws layout (float offsets)
#define OFF_LN   0                      // ln_feat [NB*D]
#define OFF_SW   (NB*D)                 // float2 sw[NB][NC]
#define OFF_MM   (OFF_SW + 2*NB*NC)     // smax[NB], smin[NB]
#define OFF_OUT1 (OFF_MM + 64)          // out1 [NB*D]
#define OFF_LN2  (OFF_OUT1 + NB*D)      // ln2  [NB*D]
#define OFF_H    (OFF_LN2 + NB*D)       // h    [NB*D]
#define OFF_P    (OFF_H + NB*D)         // partials [16][NB*D] = 4 MB

__device__ __forceinline__ float wred_sum(float x){
  #pragma unroll
  for (int o = 32; o; o >>= 1) x += __shfl_xor(x, o);
  return x;
}

// ---------------------------------------------------------------------------
// Kernel 1: per-batch prep. LN1, gather, kq/vw fold, s/w vectors, smax/smin.
// ---------------------------------------------------------------------------
__global__ __launch_bounds__(256) void prep_kernel(
    const float* __restrict__ feat, const int* __restrict__ idx,
    const float* __restrict__ ln_w, const float* __restrict__ ln_b,
    const float* __restrict__ q_w,  const float* __restrict__ k_w,
    const float* __restrict__ v_w,  const float* __restrict__ conv_w,
    float* __restrict__ ws)
{
  __shared__ float sh_feat[D];
  __shared__ float sh_shuf[D];
  __shared__ float red_s[4][2];
  __shared__ float red_k[4][8];
  __shared__ float red_mm[4][2];

  const int b = blockIdx.x;
  const int t = threadIdx.x;
  const int wid = t >> 6;

  const float4* fb4 = (const float4*)(feat + b * D);
  float4* sf4 = (float4*)sh_feat;
  float4 fv[2];
  float s1 = 0.f, s2 = 0.f;
  #pragma unroll
  for (int j = 0; j < 2; ++j) {
    float4 v = fb4[t + j * 256];
    fv[j] = v;
    sf4[t + j * 256] = v;
    s1 += (v.x + v.y) + (v.z + v.w);
    s2 += fmaf(v.x, v.x, fmaf(v.y, v.y, fmaf(v.z, v.z, v.w * v.w)));
  }

  float pk[4] = {0,0,0,0}, pv[4] = {0,0,0,0};
  if (t < 128) {
    float qv = q_w[t], cv = conv_w[t];
    #pragma unroll
    for (int j = 0; j < 4; ++j) {
      pk[j] = qv * k_w[t * 4 + j];
      pv[j] = cv * v_w[t * 4 + j];
    }
  }
  s1 = wred_sum(s1); s2 = wred_sum(s2);
  #pragma unroll
  for (int j = 0; j < 4; ++j) { pk[j] = wred_sum(pk[j]); pv[j] = wred_sum(pv[j]); }
  if ((t & 63) == 0) {
    red_s[wid][0] = s1; red_s[wid][1] = s2;
    #pragma unroll
    for (int j = 0; j < 4; ++j) { red_k[wid][j] = pk[j]; red_k[wid][4 + j] = pv[j]; }
  }
  __syncthreads();

  const float S1 = red_s[0][0] + red_s[1][0] + red_s[2][0] + red_s[3][0];
  const float S2 = red_s[0][1] + red_s[1][1] + red_s[2][1] + red_s[3][1];
  float kq[4], vw[4];
  #pragma unroll
  for (int j = 0; j < 4; ++j) {
    kq[j] = red_k[0][j] + red_k[1][j] + red_k[2][j] + red_k[3][j];
    vw[j] = red_k[0][4+j] + red_k[1][4+j] + red_k[2][4+j] + red_k[3][4+j];
  }
  const float mean = S1 * (1.f / D);
  const float rstd = rsqrtf(S2 * (1.f / D) - mean * mean + 1e-5f);

  float* lnp = ws + OFF_LN + b * D;
  const float4* lw4 = (const float4*)ln_w;
  const float4* lb4 = (const float4*)ln_b;
  #pragma unroll
  for (int j = 0; j < 2; ++j) {
    int i = t + j * 256;
    float4 v = fv[j], w = lw4[i], bb = lb4[i], o;
    o.x = (v.x - mean) * rstd * w.x + bb.x;
    o.y = (v.y - mean) * rstd * w.y + bb.y;
    o.z = (v.z - mean) * rstd * w.z + bb.z;
    o.w = (v.w - mean) * rstd * w.w + bb.w;
    ((float4*)lnp)[i] = o;
  }

  #pragma unroll
  for (int j = 0; j < 8; ++j) {
    int i = t + j * 256;
    sh_shuf[i] = sh_feat[idx[i]];
  }
  __syncthreads();

  float2* swp = (float2*)(ws + OFF_SW) + b * NC;
  float lmax = -FLT_MAX, lmin = FLT_MAX;
  #pragma unroll
  for (int j = 0; j < 4; ++j) {
    int c = t + j * 256;
    if (c < NC) {
      float a0 = sh_shuf[2*c], a1 = sh_shuf[2*c+1], a2 = sh_shuf[2*c+2], a3 = sh_shuf[2*c+3];
      float sv = fmaf(a0, kq[0], fmaf(a1, kq[1], fmaf(a2, kq[2], a3 * kq[3])));
      float wv = fmaf(a0, vw[0], fmaf(a1, vw[1], fmaf(a2, vw[2], a3 * vw[3])));
      float2 p; p.x = sv; p.y = wv;
      swp[c] = p;
      lmax = fmaxf(lmax, sv);
      lmin = fminf(lmin, sv);
    }
  }
  #pragma unroll
  for (int o = 32; o; o >>= 1) {
    lmax = fmaxf(lmax, __shfl_xor(lmax, o));
    lmin = fminf(lmin, __shfl_xor(lmin, o));
  }
  if ((t & 63) == 0) { red_mm[wid][0] = lmax; red_mm[wid][1] = lmin; }
  __syncthreads();
  if (t == 0) {
    ws[OFF_MM + b]      = fmaxf(fmaxf(red_mm[0][0], red_mm[1][0]), fmaxf(red_mm[2][0], red_mm[3][0]));
    ws[OFF_MM + NB + b] = fminf(fminf(red_mm[0][1], red_mm[1][1]), fminf(red_mm[2][1], red_mm[3][1]));
  }
}

// ---------------------------------------------------------------------------
// Kernel 2: 8 rows per block. sw staged in LDS once; exp pass into flat LDS;
// contiguous aligned float4 nontemporal stores.
// ---------------------------------------------------------------------------
__global__ __launch_bounds__(256) void attn_kernel(
    const float* __restrict__ feat, float* __restrict__ ws,
    float* __restrict__ out)
{
  __shared__ float ebuf[RPB * 1024];
  __shared__ float2 sws[1024];
  __shared__ float sinv[RPB];

  const int row0 = blockIdx.x * RPB;
  const int b = row0 >> 11;
  const int t = threadIdx.x;
  const int wid = t >> 6, lane = t & 63;

  const float smax = ws[OFF_MM + b], smin = ws[OFF_MM + NB + b];
  const float2* swg = (const float2*)(ws + OFF_SW) + b * NC;
  #pragma unroll
  for (int j = 0; j < 4; ++j) {
    int c = t + j * 256;
    if (c < NC) sws[c] = swg[c];
  }
  __syncthreads();

  #pragma unroll
  for (int rr = 0; rr < 2; ++rr) {
    const int r = wid * 2 + rr;
    const int row = row0 + r;
    const float alpha = ws[OFF_LN + row];
    const float m = (alpha >= 0.f) ? alpha * smax : alpha * smin;
    float* eb = ebuf + r * NC;
    float l = 0.f, acc = 0.f;
    #pragma unroll
    for (int j = 0; j < 16; ++j) {
      int c = lane + j * 64;
      if (c < NC) {
        float2 p = sws[c];
        float e = __expf(fmaf(alpha, p.x, -m));
        eb[c] = e;
        l += e;
        acc = fmaf(e, p.y, acc);
      }
    }
    #pragma unroll
    for (int o = 32; o; o >>= 1) { l += __shfl_xor(l, o); acc += __shfl_xor(acc, o); }
    if (lane == 0) {
      float inv = 1.f / l;
      sinv[r] = inv;
      ws[OFF_OUT1 + row] = fmaf(acc, inv, feat[row]);
    }
  }
  __syncthreads();

  f32x4* base = (f32x4*)(out + NB * D + (size_t)row0 * NC);
  const f32x4* eb4 = (const f32x4*)ebuf;
  #pragma unroll
  for (int j = 0; j < 8; ++j) {
    int i4 = t + j * 256;
    if (i4 < 2046) {
      f32x4 v = eb4[i4];
      int g = i4 * 4;
      int r0 = g / NC;               // one magic-mul divide
      int rem = g - r0 * NC;         // 0..1022
      float i0 = sinv[r0];
      float i1 = sinv[r0 + (rem >= NC - 1)];
      float i2 = sinv[r0 + (rem >= NC - 2)];
      float i3 = sinv[r0 + (rem >= NC - 3)];
      v.x *= i0; v.y *= i1; v.z *= i2; v.w *= i3;
      __builtin_nontemporal_store(v, base + i4);
    }
  }
}

// ---------------------------------------------------------------------------
// Kernel 3: LN2 over out1 -> ln2.
// ---------------------------------------------------------------------------
__global__ __launch_bounds__(256) void ln2_kernel(
    const float* __restrict__ bnw, const float* __restrict__ bnb,
    float* __restrict__ ws)
{
  __shared__ float red_s[4][2];
  const int b = blockIdx.x, t = threadIdx.x;
  const int wid = t >> 6;
  const float4* x4 = (const float4*)(ws + OFF_OUT1 + b * D);
  float4 xv[2];
  float s1 = 0.f, s2 = 0.f;
  #pragma unroll
  for (int j = 0; j < 2; ++j) {
    float4 v = x4[t + j * 256];
    xv[j] = v;
    s1 += (v.x + v.y) + (v.z + v.w);
    s2 += fmaf(v.x, v.x, fmaf(v.y, v.y, fmaf(v.z, v.z, v.w * v.w)));
  }
  s1 = wred_sum(s1); s2 = wred_sum(s2);
  if ((t & 63) == 0) { red_s[wid][0] = s1; red_s[wid][1] = s2; }
  __syncthreads();
  const float S1 = red_s[0][0] + red_s[1][0] + red_s[2][0] + red_s[3][0];
  const float S2 = red_s[0][1] + red_s[1][1] + red_s[2][1] + red_s[3][1];
  const float mean = S1 * (1.f / D);
  const float rstd = rsqrtf(S2 * (1.f / D) - mean * mean + 1e-6f);

  float4* ln2p = (float4*)(ws + OFF_LN2 + b * D);
  const float4* bw4 = (const float4*)bnw;
  const float4* bb4 = (const float4*)bnb;
  #pragma unroll
  for (int j = 0; j < 2; ++j) {
    int i = t + j * 256;
    float4 v = xv[j], w = bw4[i], bb = bb4[i], o;
    o.x = (v.x - mean) * rstd * w.x + bb.x;
    o.y = (v.y - mean) * rstd * w.y + bb.y;
    o.z = (v.z - mean) * rstd * w.z + bb.z;
    o.w = (v.w - mean) * rstd * w.w + bb.w;
    ln2p[i] = o;
  }
}

// ---------------------------------------------------------------------------
// Kernels 4/6: partial[kb][m][n] = sum_{k in chunk} X[m,k]*W[n,k]
// grid = 32 nb (N=64) x 16 kb (K=128), 128 threads, 4x4 register tiles.
// NO atomics: each block writes its own partial slab with float4 stores.
// ---------------------------------------------------------------------------
__global__ __launch_bounds__(128) void gemm_kernel(
    const float* __restrict__ X, const float* __restrict__ W,
    float* __restrict__ P)
{
  __shared__ float xs[32][132];     // 32 m x 128 k (pad 132)
  __shared__ float wtT[128 * 64];   // [k][n] swizzled
  const int nb = blockIdx.x & 31;
  const int kb = blockIdx.x >> 5;   // 0..15
  const int n0 = nb * 64;
  const int k0 = kb * 128;
  const int t = threadIdx.x;        // 0..127
  const int tm = t >> 4;            // 0..7
  const int tn = t & 15;            // 0..15

  #pragma unroll
  for (int jj = 0; jj < 8; ++jj) {
    int idx = jj * 128 + t;
    int m_r = idx >> 5, q_r = idx & 31;
    float4 v = *(const float4*)(X + m_r * 2048 + k0 + q_r * 4);
    *(float4*)(&xs[m_r][q_r * 4]) = v;
  }
  #pragma unroll
  for (int jj = 0; jj < 16; ++jj) {
    int idx = jj * 128 + t;
    int n_r = idx >> 5, q_r = idx & 31;
    float4 v = *(const float4*)(W + (n0 + n_r) * 2048 + k0 + q_r * 4);
    float vv[4] = {v.x, v.y, v.z, v.w};
    #pragma unroll
    for (int c = 0; c < 4; ++c) {
      int kk = q_r * 4 + c;
      wtT[kk * 64 + ((((n_r >> 2) ^ (kk & 15)) << 2) | (n_r & 3))] = vv[c];
    }
  }
  __syncthreads();

  float4 acc0 = {0,0,0,0}, acc1 = {0,0,0,0}, acc2 = {0,0,0,0}, acc3 = {0,0,0,0};
  #pragma unroll 2
  for (int kq = 0; kq < 32; ++kq) {
    float4 xq0 = *(const float4*)(&xs[tm * 4 + 0][kq * 4]);
    float4 xq1 = *(const float4*)(&xs[tm * 4 + 1][kq * 4]);
    float4 xq2 = *(const float4*)(&xs[tm * 4 + 2][kq * 4]);
    float4 xq3 = *(const float4*)(&xs[tm * 4 + 3][kq * 4]);
    #pragma unroll
    for (int c = 0; c < 4; ++c) {
      int kk = kq * 4 + c;
      float4 wv = *(const float4*)(&wtT[kk * 64 + ((tn ^ (kk & 15)) << 2)]);
      float x0 = (c==0)?xq0.x:(c==1)?xq0.y:(c==2)?xq0.z:xq0.w;
      float x1 = (c==0)?xq1.x:(c==1)?xq1.y:(c==2)?xq1.z:xq1.w;
      float x2 = (c==0)?xq2.x:(c==1)?xq2.y:(c==2)?xq2.z:xq2.w;
      float x3 = (c==0)?xq3.x:(c==1)?xq3.y:(c==2)?xq3.z:xq3.w;
      acc0.x = fmaf(x0, wv.x, acc0.x); acc0.y = fmaf(x0, wv.y, acc0.y);
      acc0.z = fmaf(x0, wv.z, acc0.z); acc0.w = fmaf(x0, wv.w, acc0.w);
      acc1.x = fmaf(x1, wv.x, acc1.x); acc1.y = fmaf(x1, wv.y, acc1.y);
      acc1.z = fmaf(x1, wv.z, acc1.z); acc1.w = fmaf(x1, wv.w, acc1.w);
      acc2.x = fmaf(x2, wv.x, acc2.x); acc2.y = fmaf(x2, wv.y, acc2.y);
      acc2.z = fmaf(x2, wv.z, acc2.z); acc2.w = fmaf(x2, wv.w, acc2.w);
      acc3.x = fmaf(x3, wv.x, acc3.x); acc3.y = fmaf(x3, wv.y, acc3.y);
      acc3.z = fmaf(x3, wv.z, acc3.z); acc3.w = fmaf(x3, wv.w, acc3.w);
    }
  }

  float* p0 = P + kb * (NB * D) + (tm * 4 + 0) * 2048 + n0 + tn * 4;
  *(float4*)(p0)          = acc0;
  *(float4*)(p0 + 2048)   = acc1;
  *(float4*)(p0 + 4096)   = acc2;
  *(float4*)(p0 + 6144)   = acc3;
}

// ---------------------------------------------------------------------------
// Kernel 5: h = relu(sum_kb P[kb] + w1_b)          (65536 elems)
// Kernel 7: out = sum_kb P[kb] + w2_b + out1       -> d_out
// ---------------------------------------------------------------------------
__global__ __launch_bounds__(256) void reduce_h_kernel(
    const float* __restrict__ ws_in, const float* __restrict__ w1b,
    float* __restrict__ ws_out)
{
  const int i4 = blockIdx.x * 256 + threadIdx.x;   // < 16384
  const float4* P4 = (const float4*)(ws_in + OFF_P);
  float4 a = P4[i4];
  #pragma unroll
  for (int kb = 1; kb < 16; ++kb) {
    float4 p = P4[kb * 16384 + i4];
    a.x += p.x; a.y += p.y; a.z += p.z; a.w += p.w;
  }
  float4 bb = ((const float4*)w1b)[i4 & 511];
  a.x = fmaxf(a.x + bb.x, 0.f);
  a.y = fmaxf(a.y + bb.y, 0.f);
  a.z = fmaxf(a.z + bb.z, 0.f);
  a.w = fmaxf(a.w + bb.w, 0.f);
  ((float4*)(ws_out + OFF_H))[i4] = a;
}

__global__ __launch_bounds__(256) void reduce_out_kernel(
    const float* __restrict__ ws_in, const float* __restrict__ w2b,
    float* __restrict__ out)
{
  const int i4 = blockIdx.x * 256 + threadIdx.x;   // < 16384
  const float4* P4 = (const float4*)(ws_in + OFF_P);
  float4 a = P4[i4];
  #pragma unroll
  for (int kb = 1; kb < 16; ++kb) {
    float4 p = P4[kb * 16384 + i4];
    a.x += p.x; a.y += p.y; a.z += p.z; a.w += p.w;
  }
  float4 bb = ((const float4*)w2b)[i4 & 511];
  float4 r  = ((const float4*)(ws_in + OFF_OUT1))[i4];
  a.x += bb.x + r.x; a.y += bb.y + r.y; a.z += bb.z + r.z; a.w += bb.w + r.w;
  ((float4*)out)[i4] = a;
}

// ---------------------------------------------------------------------------
extern "C" void kernel_launch(void* const* d_in, const int* in_sizes, int n_in,
                              void* d_out, int out_size, void* d_ws, size_t ws_size,
                              hipStream_t stream)
{
  (void)in_sizes; (void)n_in; (void)out_size; (void)ws_size;
  const float* feat   = (const float*)d_in[0];
  const int*   idx    = (const int*)d_in[1];
  const float* ln_w   = (const float*)d_in[2];
  const float* ln_b   = (const float*)d_in[3];
  const float* q_w    = (const float*)d_in[4];
  const float* k_w    = (const float*)d_in[5];
  const float* v_w    = (const float*)d_in[6];
  const float* conv_w = (const float*)d_in[7];
  const float* bnw    = (const float*)d_in[8];
  const float* bnb    = (const float*)d_in[9];
  const float* w1w    = (const float*)d_in[10];
  const float* w1b    = (const float*)d_in[11];
  const float* w2w    = (const float*)d_in[12];
  const float* w2b    = (const float*)d_in[13];
  float* out = (float*)d_out;
  float* ws  = (float*)d_ws;

  prep_kernel<<<dim3(NB), dim3(256), 0, stream>>>(feat, idx, ln_w, ln_b, q_w, k_w, v_w, conv_w, ws);
  attn_kernel<<<dim3(NB * D / RPB), dim3(256), 0, stream>>>(feat, ws, out);
  ln2_kernel<<<dim3(NB), dim3(256), 0, stream>>>(bnw, bnb, ws);
  gemm_kernel<<<dim3(512), dim3(128), 0, stream>>>(ws + OFF_LN2, w1w, ws + OFF_P);
  reduce_h_kernel<<<dim3(64), dim3(256), 0, stream>>>(ws, w1b, ws);
  gemm_kernel<<<dim3(512), dim3(128), 0, stream>>>(ws + OFF_H, w2w, ws + OFF_P);
  reduce_out_kernel<<<dim3(64), dim3(256), 0, stream>>>(ws, w2b, out);
}